// Round 11
// baseline (258.541 us; speedup 1.0000x reference)
//
#include <hip/hip_runtime.h>

#define DIM 768
#define NHEADS 12
#define HDIM 64
#define BB 16
#define NN 784
#define M_TOTAL (BB * NN)   // 12544

typedef __attribute__((ext_vector_type(8))) _Float16 f16x8;
typedef __attribute__((ext_vector_type(4))) float f32x4;
typedef __attribute__((ext_vector_type(16))) float f32x16;
typedef __fp16 fp16x2 __attribute__((ext_vector_type(2)));

// ---- async global->LDS, 16B per lane ------------------------------------
typedef __attribute__((address_space(3))) unsigned int lds_uint;
typedef __attribute__((address_space(1))) const unsigned int g_uint;
__device__ inline void gload_lds16(const void* g, void* l) {
    __builtin_amdgcn_global_load_lds((g_uint*)(uintptr_t)g,
                                     (lds_uint*)(uintptr_t)l, 16, 0, 0);
}

#if __has_builtin(__builtin_amdgcn_exp2f)
#define EXP2(x) __builtin_amdgcn_exp2f(x)
#else
#define EXP2(x) exp2f(x)
#endif

// pack 2 f32 -> u32 of 2 f16 (RTZ) and accumulate both into *lacc
__device__ inline unsigned int pk2(float a, float b, float* lacc) {
#if __has_builtin(__builtin_amdgcn_cvt_pkrtz)
    union { fp16x2 h; unsigned int u; } r;
    r.h = __builtin_amdgcn_cvt_pkrtz(a, b);
#if __has_builtin(__builtin_amdgcn_fdot2)
    const fp16x2 one = {(__fp16)1.f, (__fp16)1.f};
    *lacc = __builtin_amdgcn_fdot2(r.h, one, *lacc, false);
#else
    *lacc += a + b;
#endif
    return r.u;
#else
    union { _Float16 h[2]; unsigned int u; } r;
    r.h[0] = (_Float16)a; r.h[1] = (_Float16)b;
    *lacc += a + b;
    return r.u;
#endif
}

// ---------------------------------------------------------------------------
// Fused prep: x f32->f16 convert + both weight transposes in ONE launch.
// Block ranges: [0,NC) cvt, [NC,NC+NQ) Wqkv^T, [NC+NQ,..) Wo^T.
// Inner bodies identical to the previous 3 kernels.
// ---------------------------------------------------------------------------
__global__ __launch_bounds__(256) void prep_kernel(
    const float* __restrict__ x, _Float16* __restrict__ xh,
    const float* __restrict__ Wqkv, _Float16* __restrict__ wqT,
    const float* __restrict__ Wo, _Float16* __restrict__ woT)
{
    const int NC  = (M_TOTAL * DIM) / (8 * 256);  // 4704
    const int NQX = (3 * DIM) / 32;               // 72
    const int NQ  = NQX * (DIM / 32);             // 1728
    const int NOX = DIM / 32;                     // 24
    const int bid = blockIdx.x;

    if (bid < NC) {
        const int i = (bid * 256 + threadIdx.x) * 8;
        float4 a = *(const float4*)&x[i];
        float4 b = *(const float4*)&x[i + 4];
        union { _Float16 h[8]; uint4 v; } o;
        o.h[0] = (_Float16)a.x; o.h[1] = (_Float16)a.y;
        o.h[2] = (_Float16)a.z; o.h[3] = (_Float16)a.w;
        o.h[4] = (_Float16)b.x; o.h[5] = (_Float16)b.y;
        o.h[6] = (_Float16)b.z; o.h[7] = (_Float16)b.w;
        *(uint4*)&xh[i] = o.v;
        return;
    }

    __shared__ float t[32][33];
    const float* W; _Float16* T; int N, n0, k0;
    if (bid < NC + NQ) {
        const int lb = bid - NC;
        W = Wqkv; T = wqT; N = 3 * DIM;
        n0 = (lb % NQX) * 32; k0 = (lb / NQX) * 32;
    } else {
        const int lb = bid - NC - NQ;
        W = Wo; T = woT; N = DIM;
        n0 = (lb % NOX) * 32; k0 = (lb / NOX) * 32;
    }
    const int K = DIM;
    const int r = threadIdx.x >> 3, c4 = (threadIdx.x & 7) * 4;
    float4 v = *(const float4*)&W[(size_t)(k0 + r) * N + n0 + c4];
    t[r][c4 + 0] = v.x; t[r][c4 + 1] = v.y;
    t[r][c4 + 2] = v.z; t[r][c4 + 3] = v.w;
    __syncthreads();
    union { _Float16 h[4]; ushort4 v4; } o;
#pragma unroll
    for (int i = 0; i < 4; ++i) o.h[i] = (_Float16)t[c4 + i][r];
    *(ushort4*)&T[(size_t)(n0 + r) * K + k0 + c4] = o.v4;
}

// ---------------------------------------------------------------------------
// f16 MFMA GEMM, 256x256 / 8 waves / BK=64 dbuf (R7 main loop, verified).
// R11: epilogue routed through the (now-idle) staging LDS in 4 column
// passes of [256][72] (72-pad: rows 16B-aligned, banks spread) -> full-row
// uint4 global stores. Replaces 128 scalar global_store_short per lane
// (WRITE_SIZE showed 76 MB vs 57.8 MB output = 1.3x half-line write
// amplification + 128 store-issues/lane).
// ---------------------------------------------------------------------------
#define SA(B) (smem + (B) * 16384)
#define SB(B) (smem + 32768 + (B) * 16384)

#define G_STAGE(BUF, K0)                                                       \
  {                                                                            \
    _Pragma("unroll")                                                          \
    for (int i = 0; i < 4; ++i) {                                              \
        const int rbase = w * 32 + i * 8;                                      \
        gload_lds16(A + (size_t)(gm + rbase + srow) * K + (K0) + scol,         \
                    SA(BUF) + rbase * 64);                                     \
        gload_lds16(B + (size_t)(gn + rbase + srow) * K + (K0) + scol,         \
                    SB(BUF) + rbase * 64);                                     \
    }                                                                          \
  }

#define G_COMPUTE(BUF)                                                         \
  {                                                                            \
    _Pragma("unroll")                                                          \
    for (int kk = 0; kk < 4; ++kk) {                                           \
        const int c = kk * 2 + hi;                                             \
        const int sw = (c ^ (l31 & 7)) * 8;                                    \
        f16x8 a[4], bb[2];                                                     \
        _Pragma("unroll")                                                      \
        for (int mt = 0; mt < 4; ++mt)                                         \
            a[mt] = *(const f16x8*)(SA(BUF) + (wm + mt * 32 + l31) * 64 + sw); \
        _Pragma("unroll")                                                      \
        for (int nt = 0; nt < 2; ++nt)                                         \
            bb[nt] = *(const f16x8*)(SB(BUF) + (wn + nt * 32 + l31) * 64 + sw);\
        __builtin_amdgcn_s_setprio(1);                                         \
        _Pragma("unroll")                                                      \
        for (int mt = 0; mt < 4; ++mt)                                         \
            _Pragma("unroll")                                                  \
            for (int nt = 0; nt < 2; ++nt)                                     \
                acc[mt][nt] = __builtin_amdgcn_mfma_f32_32x32x16_f16(          \
                    a[mt], bb[nt], acc[mt][nt], 0, 0, 0);                      \
        __builtin_amdgcn_s_setprio(0);                                         \
    }                                                                          \
  }

template <int OUT_F16>
__global__ __launch_bounds__(512) void gemm_f16_kernel(
    const _Float16* __restrict__ A, const _Float16* __restrict__ B,
    const float* __restrict__ bias, void* __restrict__ Cout,
    int M, int N, int K)
{
    __shared__ _Float16 smem[4 * 256 * 64];   // A dbuf | B dbuf; epilogue buf

    const int tid  = threadIdx.x;
    const int w    = tid >> 6;
    const int lane = tid & 63;

    const int nwg = gridDim.x * gridDim.y;
    const int lid = blockIdx.x + gridDim.x * blockIdx.y;
    const int cq  = nwg >> 3, cr = nwg & 7;
    const int xcd = lid & 7, ix = lid >> 3;
    const int wgid = (xcd < cr ? xcd * (cq + 1) : cr * (cq + 1) + (xcd - cr) * cq) + ix;
    const int gn = (wgid % gridDim.x) * 256;
    const int gm = (wgid / gridDim.x) * 256;

    const int wm = (w & 1) * 128;
    const int wn = (w >> 1) * 64;
    const int l31 = lane & 31;
    const int hi  = lane >> 5;

    const int srow = lane >> 3;
    const int scol = ((lane & 7) ^ srow) * 8;

    f32x16 acc[4][2] = {};

    const int NT = K >> 6;
    G_STAGE(0, 0)
    __syncthreads();
    int cur = 0;
#pragma unroll 1
    for (int t = 0; t < NT - 1; ++t) {
        G_STAGE(cur ^ 1, (t + 1) * 64)
        G_COMPUTE(cur)
        __syncthreads();
        cur ^= 1;
    }
    G_COMPUTE(cur)
    __syncthreads();   // all smem reads done before epilogue reuse

    // ---- LDS-coalesced epilogue: pass q covers cols gn+q*64 .. +63.
    // Writers: the 2 waves with (w>>1)==q (their wn == q*64); all 512
    // threads then read rows and store contiguous 64B(f16)/128B(f32) segs.
#pragma unroll 1
    for (int q = 0; q < 4; ++q) {
        if ((w >> 1) == q) {
            if (OUT_F16) {
                _Float16* eb = (_Float16*)smem;            // [256][72]
#pragma unroll
                for (int nt = 0; nt < 2; ++nt) {
                    const float bv = bias[gn + q * 64 + nt * 32 + l31];
#pragma unroll
                    for (int mt = 0; mt < 4; ++mt) {
                        f32x16 v = acc[mt][nt];
#pragma unroll
                        for (int reg = 0; reg < 16; ++reg) {
                            const int row = wm + mt * 32 + (reg & 3) + 8 * (reg >> 2) + 4 * hi;
                            eb[row * 72 + nt * 32 + l31] = (_Float16)(v[reg] + bv);
                        }
                    }
                }
            } else {
                float* eb = (float*)smem;                  // [256][72]
#pragma unroll
                for (int nt = 0; nt < 2; ++nt) {
                    const float bv = bias[gn + q * 64 + nt * 32 + l31];
#pragma unroll
                    for (int mt = 0; mt < 4; ++mt) {
                        f32x16 v = acc[mt][nt];
#pragma unroll
                        for (int reg = 0; reg < 16; ++reg) {
                            const int row = wm + mt * 32 + (reg & 3) + 8 * (reg >> 2) + 4 * hi;
                            eb[row * 72 + nt * 32 + l31] = v[reg] + bv;
                        }
                    }
                }
            }
        }
        __syncthreads();
        {
            const int row = tid >> 1, seg = tid & 1;       // 2 thr/row
            if (OUT_F16) {
                const _Float16* eb = (const _Float16*)smem;
                _Float16* cp = (_Float16*)Cout + (size_t)(gm + row) * N
                             + gn + q * 64 + seg * 32;
                const _Float16* sp = eb + row * 72 + seg * 32;   // 64B seg
#pragma unroll
                for (int k = 0; k < 4; ++k)
                    *(uint4*)(cp + k * 8) = *(const uint4*)(sp + k * 8);
            } else {
                const float* eb = (const float*)smem;
                float* cp = (float*)Cout + (size_t)(gm + row) * N
                          + gn + q * 64 + seg * 32;
                const float* sp = eb + row * 72 + seg * 32;      // 128B seg
#pragma unroll
                for (int k = 0; k < 8; ++k)
                    *(uint4*)(cp + k * 4) = *(const uint4*)(sp + k * 4);
            }
        }
        __syncthreads();
    }
}

// ---------------------------------------------------------------------------
// f16 MFMA flash attention (unchanged from R5-R10).
// ---------------------------------------------------------------------------
#define LOG2E_8 0.18033688f  // 0.125 * log2(e)

#define LOAD_TILE(J0, TAIL)                                                    \
  {                                                                            \
    const int j0_ = (J0);                                                      \
    int jrowK = j0_ + sj;                                                      \
    if (TAIL && jrowK > NN - 1) jrowK = NN - 1;                                \
    const size_t kbase = (size_t)(b * NN + jrowK) * (3 * DIM) + DIM + h * HDIM;\
    k0v = *(const uint4*)&qkv[kbase + sg * 8];                                 \
    k1v = *(const uint4*)&qkv[kbase + sg * 8 + 32];                            \
    int vr0 = j0_ + 2 * jj, vr1 = j0_ + 2 * jj + 1;                            \
    if (TAIL) { if (vr0 > NN - 1) vr0 = NN - 1; if (vr1 > NN - 1) vr1 = NN - 1; } \
    va.v = *(const uint4*)&qkv[(size_t)(b * NN + vr0) * (3 * DIM) + 2 * DIM + h * HDIM + dsub]; \
    vc.v = *(const uint4*)&qkv[(size_t)(b * NN + vr1) * (3 * DIM) + 2 * DIM + h * HDIM + dsub]; \
  }

#define WRITE_TILE(BUF)                                                        \
  {                                                                            \
    _Float16 (*K_)[72] = Ks[BUF];                                              \
    _Float16 (*V_)[72] = Vt[BUF];                                              \
    *(uint4*)&K_[sj][sg * 8]      = k0v;                                       \
    *(uint4*)&K_[sj][sg * 8 + 32] = k1v;                                       \
    _Pragma("unroll")                                                          \
    for (int i = 0; i < 8; ++i) {                                              \
        union { _Float16 h2[2]; unsigned int u; } t;                           \
        t.h2[0] = va.h[i]; t.h2[1] = vc.h[i];                                  \
        *(unsigned int*)&V_[dsub + i][pcol] = t.u;                             \
    }                                                                          \
  }

#define EXP_PACK(SV, G, J0_, TAIL)                                             \
  {                                                                            \
    float p0 = EXP2(SV[0]), p1 = EXP2(SV[1]);                                  \
    float p2 = EXP2(SV[2]), p3 = EXP2(SV[3]);                                  \
    if (TAIL && (J0_ + nt * 16) >= NN) { p0 = p1 = p2 = p3 = 0.f; }            \
    pk[G][nt][0] = pk2(p0, p1, &lpart[G]);                                     \
    pk[G][nt][1] = pk2(p2, p3, &lpart[G]);                                     \
  }

#define COMPUTE_TILE(BUF, J0, TAIL)                                            \
  {                                                                            \
    _Float16 (*K_)[72] = Ks[BUF];                                              \
    _Float16 (*V_)[72] = Vt[BUF];                                              \
    unsigned int pk[2][4][2];                                                  \
    _Pragma("unroll")                                                          \
    for (int nt = 0; nt < 4; ++nt) {                                           \
        f16x8 kf0 = *(const f16x8*)&K_[nt * 16 + l16][quad * 8];               \
        f16x8 kf1 = *(const f16x8*)&K_[nt * 16 + l16][32 + quad * 8];          \
        f32x4 s0 = {}, s1 = {};                                                \
        s0 = __builtin_amdgcn_mfma_f32_16x16x32_f16(kf0, qfrag[0][0], s0, 0, 0, 0); \
        s0 = __builtin_amdgcn_mfma_f32_16x16x32_f16(kf1, qfrag[0][1], s0, 0, 0, 0); \
        s1 = __builtin_amdgcn_mfma_f32_16x16x32_f16(kf0, qfrag[1][0], s1, 0, 0, 0); \
        s1 = __builtin_amdgcn_mfma_f32_16x16x32_f16(kf1, qfrag[1][1], s1, 0, 0, 0); \
        EXP_PACK(s0, 0, J0, TAIL)                                              \
        EXP_PACK(s1, 1, J0, TAIL)                                              \
    }                                                                          \
    __builtin_amdgcn_s_setprio(1);                                             \
    _Pragma("unroll")                                                          \
    for (int pc = 0; pc < 2; ++pc) {                                           \
        union { unsigned int u[4]; f16x8 v; } pa0, pa1;                        \
        pa0.u[0] = pk[0][2 * pc][0];     pa0.u[1] = pk[0][2 * pc][1];          \
        pa0.u[2] = pk[0][2 * pc + 1][0]; pa0.u[3] = pk[0][2 * pc + 1][1];      \
        pa1.u[0] = pk[1][2 * pc][0];     pa1.u[1] = pk[1][2 * pc][1];          \
        pa1.u[2] = pk[1][2 * pc + 1][0]; pa1.u[3] = pk[1][2 * pc + 1][1];      \
        _Pragma("unroll")                                                      \
        for (int dt = 0; dt < 4; ++dt) {                                       \
            f16x8 vf = *(const f16x8*)&V_[dt * 16 + l16][pc * 32 + quad * 8];  \
            O[0][dt] = __builtin_amdgcn_mfma_f32_16x16x32_f16(pa0.v, vf, O[0][dt], 0, 0, 0); \
            O[1][dt] = __builtin_amdgcn_mfma_f32_16x16x32_f16(pa1.v, vf, O[1][dt], 0, 0, 0); \
        }                                                                      \
    }                                                                          \
    __builtin_amdgcn_s_setprio(0);                                             \
  }

__global__ __launch_bounds__(256, 2) void attn_f16_kernel(
    const _Float16* __restrict__ qkv, _Float16* __restrict__ oat)
{
    const int L   = blockIdx.x + 7 * (blockIdx.y + NHEADS * blockIdx.z);
    const int xcd = L & 7, ixc = L >> 3;
    const int grp = xcd * 24 + ixc / 7;
    const int q0  = (ixc % 7) * 128;
    const int b   = grp / NHEADS;
    const int h   = grp % NHEADS;

    const int tid = threadIdx.x;
    const int wave = tid >> 6;
    const int lane = tid & 63;
    const int quad = lane >> 4;
    const int l16  = lane & 15;

    __shared__ _Float16 Ks[2][64][72];
    __shared__ _Float16 Vt[2][64][72];

    f16x8 qfrag[2][2];
#pragma unroll
    for (int g = 0; g < 2; ++g) {
        int qrow = q0 + wave * 32 + g * 16 + l16; if (qrow > NN - 1) qrow = NN - 1;
        size_t base = (size_t)(b * NN + qrow) * (3 * DIM) + h * HDIM;
        qfrag[g][0] = (*(const f16x8*)&qkv[base + quad * 8]) * (_Float16)LOG2E_8;
        qfrag[g][1] = (*(const f16x8*)&qkv[base + 32 + quad * 8]) * (_Float16)LOG2E_8;
    }

    const int sj = lane;
    const int sg = wave;
    const int jj   = lane & 31;
    const int dsub = sg * 16 + (lane >> 5) * 8;
    const int pcol = ((jj >> 4) << 5) | (((jj >> 1) & 3) << 3)
                   | (((jj >> 3) & 1) << 2) | ((jj & 1) << 1);

    f32x4 O[2][4] = {};
    float lpart[2] = {0.f, 0.f};

    uint4 k0v, k1v;
    union { uint4 v; _Float16 h[8]; } va, vc;

    LOAD_TILE(0, 0)
#pragma unroll 1
    for (int jt = 0; jt < 11; ++jt) {
        WRITE_TILE(jt & 1)
        __syncthreads();
        LOAD_TILE((jt + 1) * 64, 0)
        COMPUTE_TILE(jt & 1, 0, 0)
    }
    WRITE_TILE(1)
    __syncthreads();
    LOAD_TILE(768, 1)
    COMPUTE_TILE(1, 704, 0)
    WRITE_TILE(0)
    __syncthreads();
    COMPUTE_TILE(0, 768, 1)

#pragma unroll
    for (int g = 0; g < 2; ++g) {
        float t = lpart[g];
        t += __shfl_xor(t, 16);
        t += __shfl_xor(t, 32);
        float inv[4];
#pragma unroll
        for (int r = 0; r < 4; ++r)
            inv[r] = 1.0f / __shfl(t, quad * 4 + r, 16);
#pragma unroll
        for (int r = 0; r < 4; ++r) {
            const int q = q0 + wave * 32 + g * 16 + quad * 4 + r;
            if (q < NN) {
#pragma unroll
                for (int dt = 0; dt < 4; ++dt) {
                    const size_t base = (size_t)(b * NN + q) * DIM + h * HDIM + dt * 16 + l16;
                    oat[base] = (_Float16)(O[g][dt][r] * inv[r]);
                }
            }
        }
    }
}

// ---------------------------------------------------------------------------
extern "C" void kernel_launch(void* const* d_in, const int* in_sizes, int n_in,
                              void* d_out, int out_size, void* d_ws, size_t ws_size,
                              hipStream_t stream) {
    const float* x    = (const float*)d_in[0];
    const float* Wqkv = (const float*)d_in[1];
    const float* bqkv = (const float*)d_in[2];
    const float* Wo   = (const float*)d_in[3];
    const float* bo   = (const float*)d_in[4];
    float* out = (float*)d_out;

    _Float16* qkv = (_Float16*)d_ws;                    // M x 2304
    _Float16* xh  = qkv + (size_t)M_TOTAL * 3 * DIM;    // M x 768
    _Float16* wqT = xh + (size_t)M_TOTAL * DIM;         // 2304 x 768
    _Float16* woT = wqT + (size_t)3 * DIM * DIM;        // 768 x 768
    _Float16* oat = xh;  // attn out reuses xh (x dead after GEMM1)

    {
        const int NC = (M_TOTAL * DIM) / (8 * 256);               // 4704
        const int NQ = ((3 * DIM) / 32) * (DIM / 32);             // 1728
        const int NO_ = (DIM / 32) * (DIM / 32);                  // 576
        prep_kernel<<<NC + NQ + NO_, 256, 0, stream>>>(
            x, xh, Wqkv, wqT, Wo, woT);
    }
    gemm_f16_kernel<1><<<dim3((3 * DIM) / 256, M_TOTAL / 256), 512, 0, stream>>>(
        xh, wqT, bqkv, qkv, M_TOTAL, 3 * DIM, DIM);
    attn_f16_kernel<<<dim3(7, NHEADS, BB), 256, 0, stream>>>(qkv, oat);
    gemm_f16_kernel<0><<<dim3(DIM / 256, M_TOTAL / 256), 512, 0, stream>>>(
        oat, woT, bo, out, M_TOTAL, DIM, DIM);
}

// Round 12
// 228.324 us; speedup vs baseline: 1.1323x; 1.1323x over previous
//
#include <hip/hip_runtime.h>

#define DIM 768
#define NHEADS 12
#define HDIM 64
#define BB 16
#define NN 784
#define M_TOTAL (BB * NN)   // 12544

typedef __attribute__((ext_vector_type(8))) _Float16 f16x8;
typedef __attribute__((ext_vector_type(4))) float f32x4;
typedef __attribute__((ext_vector_type(16))) float f32x16;
typedef __fp16 fp16x2 __attribute__((ext_vector_type(2)));

// ---- async global->LDS, 16B per lane ------------------------------------
typedef __attribute__((address_space(3))) unsigned int lds_uint;
typedef __attribute__((address_space(1))) const unsigned int g_uint;
__device__ inline void gload_lds16(const void* g, void* l) {
    __builtin_amdgcn_global_load_lds((g_uint*)(uintptr_t)g,
                                     (lds_uint*)(uintptr_t)l, 16, 0, 0);
}

#if __has_builtin(__builtin_amdgcn_exp2f)
#define EXP2(x) __builtin_amdgcn_exp2f(x)
#else
#define EXP2(x) exp2f(x)
#endif

// pack 2 f32 -> u32 of 2 f16 (RTZ) and accumulate both into *lacc
__device__ inline unsigned int pk2(float a, float b, float* lacc) {
#if __has_builtin(__builtin_amdgcn_cvt_pkrtz)
    union { fp16x2 h; unsigned int u; } r;
    r.h = __builtin_amdgcn_cvt_pkrtz(a, b);
#if __has_builtin(__builtin_amdgcn_fdot2)
    const fp16x2 one = {(__fp16)1.f, (__fp16)1.f};
    *lacc = __builtin_amdgcn_fdot2(r.h, one, *lacc, false);
#else
    *lacc += a + b;
#endif
    return r.u;
#else
    union { _Float16 h[2]; unsigned int u; } r;
    r.h[0] = (_Float16)a; r.h[1] = (_Float16)b;
    *lacc += a + b;
    return r.u;
#endif
}

// ---------------------------------------------------------------------------
// Fused prep: x f32->f16 convert + both weight transposes in ONE launch.
// (kept from R11 — launch-count reduction; inner bodies unchanged/verified)
// ---------------------------------------------------------------------------
__global__ __launch_bounds__(256) void prep_kernel(
    const float* __restrict__ x, _Float16* __restrict__ xh,
    const float* __restrict__ Wqkv, _Float16* __restrict__ wqT,
    const float* __restrict__ Wo, _Float16* __restrict__ woT)
{
    const int NC  = (M_TOTAL * DIM) / (8 * 256);  // 4704
    const int NQX = (3 * DIM) / 32;               // 72
    const int NQ  = NQX * (DIM / 32);             // 1728
    const int NOX = DIM / 32;                     // 24
    const int bid = blockIdx.x;

    if (bid < NC) {
        const int i = (bid * 256 + threadIdx.x) * 8;
        float4 a = *(const float4*)&x[i];
        float4 b = *(const float4*)&x[i + 4];
        union { _Float16 h[8]; uint4 v; } o;
        o.h[0] = (_Float16)a.x; o.h[1] = (_Float16)a.y;
        o.h[2] = (_Float16)a.z; o.h[3] = (_Float16)a.w;
        o.h[4] = (_Float16)b.x; o.h[5] = (_Float16)b.y;
        o.h[6] = (_Float16)b.z; o.h[7] = (_Float16)b.w;
        *(uint4*)&xh[i] = o.v;
        return;
    }

    __shared__ float t[32][33];
    const float* W; _Float16* T; int N, n0, k0;
    if (bid < NC + NQ) {
        const int lb = bid - NC;
        W = Wqkv; T = wqT; N = 3 * DIM;
        n0 = (lb % NQX) * 32; k0 = (lb / NQX) * 32;
    } else {
        const int lb = bid - NC - NQ;
        W = Wo; T = woT; N = DIM;
        n0 = (lb % NOX) * 32; k0 = (lb / NOX) * 32;
    }
    const int K = DIM;
    const int r = threadIdx.x >> 3, c4 = (threadIdx.x & 7) * 4;
    float4 v = *(const float4*)&W[(size_t)(k0 + r) * N + n0 + c4];
    t[r][c4 + 0] = v.x; t[r][c4 + 1] = v.y;
    t[r][c4 + 2] = v.z; t[r][c4 + 3] = v.w;
    __syncthreads();
    union { _Float16 h[4]; ushort4 v4; } o;
#pragma unroll
    for (int i = 0; i < 4; ++i) o.h[i] = (_Float16)t[c4 + i][r];
    *(ushort4*)&T[(size_t)(n0 + r) * K + k0 + c4] = o.v4;
}

// ---------------------------------------------------------------------------
// f16 MFMA GEMM, 256x256 / 8 waves / BK=64 dbuf — exact R7 (verified 64.4us
// GEMM1). Direct-store epilogue restored: R11's LDS-coalesced epilogue cut
// WRITE_SIZE 76->56 MB but cost 16us (4 serialized passes, 6/8 waves idle);
// the amplification was only ~3us of HBM time. Keep direct stores.
// ---------------------------------------------------------------------------
#define G_STAGE(BUF, K0)                                                       \
  {                                                                            \
    _Pragma("unroll")                                                          \
    for (int i = 0; i < 4; ++i) {                                              \
        const int rbase = w * 32 + i * 8;                                      \
        gload_lds16(A + (size_t)(gm + rbase + srow) * K + (K0) + scol,         \
                    &sA[BUF][rbase * 64]);                                     \
        gload_lds16(B + (size_t)(gn + rbase + srow) * K + (K0) + scol,         \
                    &sB[BUF][rbase * 64]);                                     \
    }                                                                          \
  }

#define G_COMPUTE(BUF)                                                         \
  {                                                                            \
    _Pragma("unroll")                                                          \
    for (int kk = 0; kk < 4; ++kk) {                                           \
        const int c = kk * 2 + hi;                                             \
        const int sw = (c ^ (l31 & 7)) * 8;                                    \
        f16x8 a[4], bb[2];                                                     \
        _Pragma("unroll")                                                      \
        for (int mt = 0; mt < 4; ++mt)                                         \
            a[mt] = *(const f16x8*)&sA[BUF][(wm + mt * 32 + l31) * 64 + sw];   \
        _Pragma("unroll")                                                      \
        for (int nt = 0; nt < 2; ++nt)                                         \
            bb[nt] = *(const f16x8*)&sB[BUF][(wn + nt * 32 + l31) * 64 + sw];  \
        __builtin_amdgcn_s_setprio(1);                                         \
        _Pragma("unroll")                                                      \
        for (int mt = 0; mt < 4; ++mt)                                         \
            _Pragma("unroll")                                                  \
            for (int nt = 0; nt < 2; ++nt)                                     \
                acc[mt][nt] = __builtin_amdgcn_mfma_f32_32x32x16_f16(          \
                    a[mt], bb[nt], acc[mt][nt], 0, 0, 0);                      \
        __builtin_amdgcn_s_setprio(0);                                         \
    }                                                                          \
  }

template <int OUT_F16>
__global__ __launch_bounds__(512) void gemm_f16_kernel(
    const _Float16* __restrict__ A, const _Float16* __restrict__ B,
    const float* __restrict__ bias, void* __restrict__ Cout,
    int M, int N, int K)
{
    __shared__ _Float16 sA[2][256 * 64];
    __shared__ _Float16 sB[2][256 * 64];

    const int tid  = threadIdx.x;
    const int w    = tid >> 6;
    const int lane = tid & 63;

    const int nwg = gridDim.x * gridDim.y;
    const int lid = blockIdx.x + gridDim.x * blockIdx.y;
    const int cq  = nwg >> 3, cr = nwg & 7;
    const int xcd = lid & 7, ix = lid >> 3;
    const int wgid = (xcd < cr ? xcd * (cq + 1) : cr * (cq + 1) + (xcd - cr) * cq) + ix;
    const int gn = (wgid % gridDim.x) * 256;
    const int gm = (wgid / gridDim.x) * 256;

    const int wm = (w & 1) * 128;
    const int wn = (w >> 1) * 64;
    const int l31 = lane & 31;
    const int hi  = lane >> 5;

    const int srow = lane >> 3;
    const int scol = ((lane & 7) ^ srow) * 8;

    f32x16 acc[4][2] = {};

    const int NT = K >> 6;
    G_STAGE(0, 0)
    __syncthreads();
    int cur = 0;
#pragma unroll 1
    for (int t = 0; t < NT - 1; ++t) {
        G_STAGE(cur ^ 1, (t + 1) * 64)
        G_COMPUTE(cur)
        __syncthreads();
        cur ^= 1;
    }
    G_COMPUTE(cur)

#pragma unroll
    for (int nt = 0; nt < 2; ++nt) {
        const int col = gn + wn + nt * 32 + l31;
        const float bv = bias[col];
#pragma unroll
        for (int mt = 0; mt < 4; ++mt) {
            f32x16 v = acc[mt][nt];
#pragma unroll
            for (int reg = 0; reg < 16; ++reg) {
                const int row = gm + wm + mt * 32 + (reg & 3) + 8 * (reg >> 2) + 4 * hi;
                const float o = v[reg] + bv;
                if (OUT_F16)
                    ((_Float16*)Cout)[(size_t)row * N + col] = (_Float16)o;
                else
                    ((float*)Cout)[(size_t)row * N + col] = o;
            }
        }
    }
}

// ---------------------------------------------------------------------------
// f16 MFMA flash attention (unchanged from R5-R11).
// ---------------------------------------------------------------------------
#define LOG2E_8 0.18033688f  // 0.125 * log2(e)

#define LOAD_TILE(J0, TAIL)                                                    \
  {                                                                            \
    const int j0_ = (J0);                                                      \
    int jrowK = j0_ + sj;                                                      \
    if (TAIL && jrowK > NN - 1) jrowK = NN - 1;                                \
    const size_t kbase = (size_t)(b * NN + jrowK) * (3 * DIM) + DIM + h * HDIM;\
    k0v = *(const uint4*)&qkv[kbase + sg * 8];                                 \
    k1v = *(const uint4*)&qkv[kbase + sg * 8 + 32];                            \
    int vr0 = j0_ + 2 * jj, vr1 = j0_ + 2 * jj + 1;                            \
    if (TAIL) { if (vr0 > NN - 1) vr0 = NN - 1; if (vr1 > NN - 1) vr1 = NN - 1; } \
    va.v = *(const uint4*)&qkv[(size_t)(b * NN + vr0) * (3 * DIM) + 2 * DIM + h * HDIM + dsub]; \
    vc.v = *(const uint4*)&qkv[(size_t)(b * NN + vr1) * (3 * DIM) + 2 * DIM + h * HDIM + dsub]; \
  }

#define WRITE_TILE(BUF)                                                        \
  {                                                                            \
    _Float16 (*K_)[72] = Ks[BUF];                                              \
    _Float16 (*V_)[72] = Vt[BUF];                                              \
    *(uint4*)&K_[sj][sg * 8]      = k0v;                                       \
    *(uint4*)&K_[sj][sg * 8 + 32] = k1v;                                       \
    _Pragma("unroll")                                                          \
    for (int i = 0; i < 8; ++i) {                                              \
        union { _Float16 h2[2]; unsigned int u; } t;                           \
        t.h2[0] = va.h[i]; t.h2[1] = vc.h[i];                                  \
        *(unsigned int*)&V_[dsub + i][pcol] = t.u;                             \
    }                                                                          \
  }

#define EXP_PACK(SV, G, J0_, TAIL)                                             \
  {                                                                            \
    float p0 = EXP2(SV[0]), p1 = EXP2(SV[1]);                                  \
    float p2 = EXP2(SV[2]), p3 = EXP2(SV[3]);                                  \
    if (TAIL && (J0_ + nt * 16) >= NN) { p0 = p1 = p2 = p3 = 0.f; }            \
    pk[G][nt][0] = pk2(p0, p1, &lpart[G]);                                     \
    pk[G][nt][1] = pk2(p2, p3, &lpart[G]);                                     \
  }

#define COMPUTE_TILE(BUF, J0, TAIL)                                            \
  {                                                                            \
    _Float16 (*K_)[72] = Ks[BUF];                                              \
    _Float16 (*V_)[72] = Vt[BUF];                                              \
    unsigned int pk[2][4][2];                                                  \
    _Pragma("unroll")                                                          \
    for (int nt = 0; nt < 4; ++nt) {                                           \
        f16x8 kf0 = *(const f16x8*)&K_[nt * 16 + l16][quad * 8];               \
        f16x8 kf1 = *(const f16x8*)&K_[nt * 16 + l16][32 + quad * 8];          \
        f32x4 s0 = {}, s1 = {};                                                \
        s0 = __builtin_amdgcn_mfma_f32_16x16x32_f16(kf0, qfrag[0][0], s0, 0, 0, 0); \
        s0 = __builtin_amdgcn_mfma_f32_16x16x32_f16(kf1, qfrag[0][1], s0, 0, 0, 0); \
        s1 = __builtin_amdgcn_mfma_f32_16x16x32_f16(kf0, qfrag[1][0], s1, 0, 0, 0); \
        s1 = __builtin_amdgcn_mfma_f32_16x16x32_f16(kf1, qfrag[1][1], s1, 0, 0, 0); \
        EXP_PACK(s0, 0, J0, TAIL)                                              \
        EXP_PACK(s1, 1, J0, TAIL)                                              \
    }                                                                          \
    __builtin_amdgcn_s_setprio(1);                                             \
    _Pragma("unroll")                                                          \
    for (int pc = 0; pc < 2; ++pc) {                                           \
        union { unsigned int u[4]; f16x8 v; } pa0, pa1;                        \
        pa0.u[0] = pk[0][2 * pc][0];     pa0.u[1] = pk[0][2 * pc][1];          \
        pa0.u[2] = pk[0][2 * pc + 1][0]; pa0.u[3] = pk[0][2 * pc + 1][1];      \
        pa1.u[0] = pk[1][2 * pc][0];     pa1.u[1] = pk[1][2 * pc][1];          \
        pa1.u[2] = pk[1][2 * pc + 1][0]; pa1.u[3] = pk[1][2 * pc + 1][1];      \
        _Pragma("unroll")                                                      \
        for (int dt = 0; dt < 4; ++dt) {                                       \
            f16x8 vf = *(const f16x8*)&V_[dt * 16 + l16][pc * 32 + quad * 8];  \
            O[0][dt] = __builtin_amdgcn_mfma_f32_16x16x32_f16(pa0.v, vf, O[0][dt], 0, 0, 0); \
            O[1][dt] = __builtin_amdgcn_mfma_f32_16x16x32_f16(pa1.v, vf, O[1][dt], 0, 0, 0); \
        }                                                                      \
    }                                                                          \
    __builtin_amdgcn_s_setprio(0);                                             \
  }

__global__ __launch_bounds__(256, 2) void attn_f16_kernel(
    const _Float16* __restrict__ qkv, _Float16* __restrict__ oat)
{
    const int L   = blockIdx.x + 7 * (blockIdx.y + NHEADS * blockIdx.z);
    const int xcd = L & 7, ixc = L >> 3;
    const int grp = xcd * 24 + ixc / 7;
    const int q0  = (ixc % 7) * 128;
    const int b   = grp / NHEADS;
    const int h   = grp % NHEADS;

    const int tid = threadIdx.x;
    const int wave = tid >> 6;
    const int lane = tid & 63;
    const int quad = lane >> 4;
    const int l16  = lane & 15;

    __shared__ _Float16 Ks[2][64][72];
    __shared__ _Float16 Vt[2][64][72];

    f16x8 qfrag[2][2];
#pragma unroll
    for (int g = 0; g < 2; ++g) {
        int qrow = q0 + wave * 32 + g * 16 + l16; if (qrow > NN - 1) qrow = NN - 1;
        size_t base = (size_t)(b * NN + qrow) * (3 * DIM) + h * HDIM;
        qfrag[g][0] = (*(const f16x8*)&qkv[base + quad * 8]) * (_Float16)LOG2E_8;
        qfrag[g][1] = (*(const f16x8*)&qkv[base + 32 + quad * 8]) * (_Float16)LOG2E_8;
    }

    const int sj = lane;
    const int sg = wave;
    const int jj   = lane & 31;
    const int dsub = sg * 16 + (lane >> 5) * 8;
    const int pcol = ((jj >> 4) << 5) | (((jj >> 1) & 3) << 3)
                   | (((jj >> 3) & 1) << 2) | ((jj & 1) << 1);

    f32x4 O[2][4] = {};
    float lpart[2] = {0.f, 0.f};

    uint4 k0v, k1v;
    union { uint4 v; _Float16 h[8]; } va, vc;

    LOAD_TILE(0, 0)
#pragma unroll 1
    for (int jt = 0; jt < 11; ++jt) {
        WRITE_TILE(jt & 1)
        __syncthreads();
        LOAD_TILE((jt + 1) * 64, 0)
        COMPUTE_TILE(jt & 1, 0, 0)
    }
    WRITE_TILE(1)
    __syncthreads();
    LOAD_TILE(768, 1)
    COMPUTE_TILE(1, 704, 0)
    WRITE_TILE(0)
    __syncthreads();
    COMPUTE_TILE(0, 768, 1)

#pragma unroll
    for (int g = 0; g < 2; ++g) {
        float t = lpart[g];
        t += __shfl_xor(t, 16);
        t += __shfl_xor(t, 32);
        float inv[4];
#pragma unroll
        for (int r = 0; r < 4; ++r)
            inv[r] = 1.0f / __shfl(t, quad * 4 + r, 16);
#pragma unroll
        for (int r = 0; r < 4; ++r) {
            const int q = q0 + wave * 32 + g * 16 + quad * 4 + r;
            if (q < NN) {
#pragma unroll
                for (int dt = 0; dt < 4; ++dt) {
                    const size_t base = (size_t)(b * NN + q) * DIM + h * HDIM + dt * 16 + l16;
                    oat[base] = (_Float16)(O[g][dt][r] * inv[r]);
                }
            }
        }
    }
}

// ---------------------------------------------------------------------------
extern "C" void kernel_launch(void* const* d_in, const int* in_sizes, int n_in,
                              void* d_out, int out_size, void* d_ws, size_t ws_size,
                              hipStream_t stream) {
    const float* x    = (const float*)d_in[0];
    const float* Wqkv = (const float*)d_in[1];
    const float* bqkv = (const float*)d_in[2];
    const float* Wo   = (const float*)d_in[3];
    const float* bo   = (const float*)d_in[4];
    float* out = (float*)d_out;

    _Float16* qkv = (_Float16*)d_ws;                    // M x 2304
    _Float16* xh  = qkv + (size_t)M_TOTAL * 3 * DIM;    // M x 768
    _Float16* wqT = xh + (size_t)M_TOTAL * DIM;         // 2304 x 768
    _Float16* woT = wqT + (size_t)3 * DIM * DIM;        // 768 x 768
    _Float16* oat = xh;  // attn out reuses xh (x dead after GEMM1)

    {
        const int NC = (M_TOTAL * DIM) / (8 * 256);               // 4704
        const int NQ = ((3 * DIM) / 32) * (DIM / 32);             // 1728
        const int NO_ = (DIM / 32) * (DIM / 32);                  // 576
        prep_kernel<<<NC + NQ + NO_, 256, 0, stream>>>(
            x, xh, Wqkv, wqT, Wo, woT);
    }
    gemm_f16_kernel<1><<<dim3((3 * DIM) / 256, M_TOTAL / 256), 512, 0, stream>>>(
        xh, wqT, bqkv, qkv, M_TOTAL, 3 * DIM, DIM);
    attn_f16_kernel<<<dim3(7, NHEADS, BB), 256, 0, stream>>>(qkv, oat);
    gemm_f16_kernel<0><<<dim3(DIM / 256, M_TOTAL / 256), 512, 0, stream>>>(
        oat, woT, bo, out, M_TOTAL, DIM, DIM);
}

// Round 13
// 224.561 us; speedup vs baseline: 1.1513x; 1.0168x over previous
//
#include <hip/hip_runtime.h>

#define DIM 768
#define NHEADS 12
#define HDIM 64
#define BB 16
#define NN 784
#define M_TOTAL (BB * NN)   // 12544

typedef __attribute__((ext_vector_type(8))) _Float16 f16x8;
typedef __attribute__((ext_vector_type(4))) float f32x4;
typedef __attribute__((ext_vector_type(16))) float f32x16;
typedef __fp16 fp16x2 __attribute__((ext_vector_type(2)));

// ---- async global->LDS, 16B per lane ------------------------------------
typedef __attribute__((address_space(3))) unsigned int lds_uint;
typedef __attribute__((address_space(1))) const unsigned int g_uint;
__device__ inline void gload_lds16(const void* g, void* l) {
    __builtin_amdgcn_global_load_lds((g_uint*)(uintptr_t)g,
                                     (lds_uint*)(uintptr_t)l, 16, 0, 0);
}

#if __has_builtin(__builtin_amdgcn_exp2f)
#define EXP2(x) __builtin_amdgcn_exp2f(x)
#else
#define EXP2(x) exp2f(x)
#endif

// pack 2 f32 -> u32 of 2 f16 (RTZ) and accumulate both into *lacc
__device__ inline unsigned int pk2(float a, float b, float* lacc) {
#if __has_builtin(__builtin_amdgcn_cvt_pkrtz)
    union { fp16x2 h; unsigned int u; } r;
    r.h = __builtin_amdgcn_cvt_pkrtz(a, b);
#if __has_builtin(__builtin_amdgcn_fdot2)
    const fp16x2 one = {(__fp16)1.f, (__fp16)1.f};
    *lacc = __builtin_amdgcn_fdot2(r.h, one, *lacc, false);
#else
    *lacc += a + b;
#endif
    return r.u;
#else
    union { _Float16 h[2]; unsigned int u; } r;
    r.h[0] = (_Float16)a; r.h[1] = (_Float16)b;
    *lacc += a + b;
    return r.u;
#endif
}

// ---------------------------------------------------------------------------
// Fused prep: x f32->f16 convert + both weight transposes in ONE launch.
// ---------------------------------------------------------------------------
__global__ __launch_bounds__(256) void prep_kernel(
    const float* __restrict__ x, _Float16* __restrict__ xh,
    const float* __restrict__ Wqkv, _Float16* __restrict__ wqT,
    const float* __restrict__ Wo, _Float16* __restrict__ woT)
{
    const int NC  = (M_TOTAL * DIM) / (8 * 256);  // 4704
    const int NQX = (3 * DIM) / 32;               // 72
    const int NQ  = NQX * (DIM / 32);             // 1728
    const int NOX = DIM / 32;                     // 24
    const int bid = blockIdx.x;

    if (bid < NC) {
        const int i = (bid * 256 + threadIdx.x) * 8;
        float4 a = *(const float4*)&x[i];
        float4 b = *(const float4*)&x[i + 4];
        union { _Float16 h[8]; uint4 v; } o;
        o.h[0] = (_Float16)a.x; o.h[1] = (_Float16)a.y;
        o.h[2] = (_Float16)a.z; o.h[3] = (_Float16)a.w;
        o.h[4] = (_Float16)b.x; o.h[5] = (_Float16)b.y;
        o.h[6] = (_Float16)b.z; o.h[7] = (_Float16)b.w;
        *(uint4*)&xh[i] = o.v;
        return;
    }

    __shared__ float t[32][33];
    const float* W; _Float16* T; int N, n0, k0;
    if (bid < NC + NQ) {
        const int lb = bid - NC;
        W = Wqkv; T = wqT; N = 3 * DIM;
        n0 = (lb % NQX) * 32; k0 = (lb / NQX) * 32;
    } else {
        const int lb = bid - NC - NQ;
        W = Wo; T = woT; N = DIM;
        n0 = (lb % NOX) * 32; k0 = (lb / NOX) * 32;
    }
    const int K = DIM;
    const int r = threadIdx.x >> 3, c4 = (threadIdx.x & 7) * 4;
    float4 v = *(const float4*)&W[(size_t)(k0 + r) * N + n0 + c4];
    t[r][c4 + 0] = v.x; t[r][c4 + 1] = v.y;
    t[r][c4 + 2] = v.z; t[r][c4 + 3] = v.w;
    __syncthreads();
    union { _Float16 h[4]; ushort4 v4; } o;
#pragma unroll
    for (int i = 0; i < 4; ++i) o.h[i] = (_Float16)t[c4 + i][r];
    *(ushort4*)&T[(size_t)(n0 + r) * K + k0 + c4] = o.v4;
}

// ---------------------------------------------------------------------------
// f16 MFMA GEMM, 256x256 / 8 waves / BK=64 dbuf, QUADRANT-PHASE schedule
// with COUNTED vmcnt (m201 structure adapted to the verified R7 layout).
//
// Why: R7/R12 sat at the 2-phase ceiling (MfmaUtil 27%) because staging is
// row-granular but k-chunk phases need ALL rows -> full drain per tile.
// Fix: phases = the wave's 4 M-blocks (mt) over FULL BK=64; B-frags read
// once into regs. Staging remapped so issue order == consumption order:
// per tile each wave issues [B0,B1,B2,B3,A0,A2,A1,A3], quarter i = rows
// i*64 + w*8 (identical physical layout/swizzle as R7).
//
// Per-wave vmem ledger (steady state, 2 issues per phase):
//   t's phases issue t+1's 8 in order B0,B1 | B2,B3 | A0,A2 | A1,A3.
//   end-p3 gate VMCNT(2)+bar: all but last 2 landed => t+1's B0-3,A0,A2
//     landed = exactly what t+1's phases 0-1 read (p=0,1 use A quarters
//     {0 or 2}: rows wm..wm+63 / 128..191).
//   end-p1 gate VMCNT(4)+bar: 4 newer issues (t+2's B0-3) outstanding =>
//     t+1's A1,A3 landed = what phases 2-3 read (rows 64-127 / 192-255).
//   vmcnt never 0 in steady state; last tile degrades to VMCNT(0) (uniform).
// Buf hazard: t+2's prefetch writes buf[t&1]; its readers (tile t) all
// passed the end-of-t boundary barrier first.
// ---------------------------------------------------------------------------
#define VMCNT(N) asm volatile("s_waitcnt vmcnt(" #N ")" ::: "memory")
#define BARRIER() { asm volatile("" ::: "memory"); \
                    __builtin_amdgcn_s_barrier();  \
                    asm volatile("" ::: "memory"); }

#define ISSUE_A(BUF, K0, I)                                                    \
    gload_lds16(A + (size_t)(gm + (I) * 64 + w * 8 + srow) * K + (K0) + scol,  \
                &sA[BUF][((I) * 64 + w * 8) * 64]);
#define ISSUE_B(BUF, K0, I)                                                    \
    gload_lds16(B + (size_t)(gn + (I) * 64 + w * 8 + srow) * K + (K0) + scol,  \
                &sB[BUF][((I) * 64 + w * 8) * 64]);

#define READ_B()                                                               \
  { _Pragma("unroll")                                                          \
    for (int kk = 0; kk < 4; ++kk) {                                           \
        const int sw = ((kk * 2 + hi) ^ (l31 & 7)) * 8;                        \
        breg[0][kk] = *(const f16x8*)&sB[cur][(wn + l31) * 64 + sw];           \
        breg[1][kk] = *(const f16x8*)&sB[cur][(wn + 32 + l31) * 64 + sw];      \
    } }

#define READ_A(P)                                                              \
  { _Pragma("unroll")                                                          \
    for (int kk = 0; kk < 4; ++kk) {                                           \
        const int sw = ((kk * 2 + hi) ^ (l31 & 7)) * 8;                        \
        af[kk] = *(const f16x8*)&sA[cur][(wm + (P) * 32 + l31) * 64 + sw];     \
    } }

#define MFMA_P(P)                                                              \
  { __builtin_amdgcn_s_setprio(1);                                             \
    _Pragma("unroll")                                                          \
    for (int kk = 0; kk < 4; ++kk) {                                           \
        acc[P][0] = __builtin_amdgcn_mfma_f32_32x32x16_f16(                    \
            af[kk], breg[0][kk], acc[P][0], 0, 0, 0);                          \
        acc[P][1] = __builtin_amdgcn_mfma_f32_32x32x16_f16(                    \
            af[kk], breg[1][kk], acc[P][1], 0, 0, 0);                          \
    }                                                                          \
    __builtin_amdgcn_s_setprio(0); }

template <int OUT_F16>
__global__ __launch_bounds__(512) void gemm_f16_kernel(
    const _Float16* __restrict__ A, const _Float16* __restrict__ B,
    const float* __restrict__ bias, void* __restrict__ Cout,
    int M, int N, int K)
{
    __shared__ _Float16 sA[2][256 * 64];
    __shared__ _Float16 sB[2][256 * 64];

    const int tid  = threadIdx.x;
    const int w    = tid >> 6;
    const int lane = tid & 63;

    // bijective XCD swizzle (m204)
    const int nwg = gridDim.x * gridDim.y;
    const int lid = blockIdx.x + gridDim.x * blockIdx.y;
    const int cq  = nwg >> 3, cr = nwg & 7;
    const int xcd = lid & 7, ix = lid >> 3;
    const int wgid = (xcd < cr ? xcd * (cq + 1) : cr * (cq + 1) + (xcd - cr) * cq) + ix;
    const int gn = (wgid % gridDim.x) * 256;
    const int gm = (wgid / gridDim.x) * 256;

    const int wm = (w & 1) * 128;        // wave tile: 128 rows x 64 cols
    const int wn = (w >> 1) * 64;
    const int l31 = lane & 31;
    const int hi  = lane >> 5;

    const int srow = lane >> 3;                       // 0..7
    const int scol = ((lane & 7) ^ srow) * 8;         // swizzled f16 col

    f32x16 acc[4][2] = {};
    f16x8 breg[2][4], af[4];

    const int NT = K >> 6;   // 12

    // prologue: tile 0 -> buf 0, issue order B0..B3, A0, A2, A1, A3
    ISSUE_B(0, 0, 0) ISSUE_B(0, 0, 1) ISSUE_B(0, 0, 2) ISSUE_B(0, 0, 3)
    ISSUE_A(0, 0, 0) ISSUE_A(0, 0, 2) ISSUE_A(0, 0, 1) ISSUE_A(0, 0, 3)
    VMCNT(2);
    BARRIER();

    int cur = 0;
#pragma unroll 1
    for (int t = 0; t < NT; ++t) {
        const int kn = (t + 1) * 64;
        const int nb = cur ^ 1;
        const bool more = (t + 1 < NT);
        // ---- phase 0 (mt=0; needs B all + A quarter {0|2})
        if (more) { ISSUE_B(nb, kn, 0) ISSUE_B(nb, kn, 1) }
        READ_B()
        READ_A(0)
        MFMA_P(0)
        // ---- phase 1 (mt=1; same quarters)
        if (more) { ISSUE_B(nb, kn, 2) ISSUE_B(nb, kn, 3) }
        READ_A(1)
        MFMA_P(1)
        if (more) { VMCNT(4); } else { VMCNT(0); }
        BARRIER();
        // ---- phase 2 (mt=2; needs A quarter {1|3})
        if (more) { ISSUE_A(nb, kn, 0) ISSUE_A(nb, kn, 2) }
        READ_A(2)
        MFMA_P(2)
        // ---- phase 3 (mt=3)
        if (more) { ISSUE_A(nb, kn, 1) ISSUE_A(nb, kn, 3) }
        READ_A(3)
        MFMA_P(3)
        if (more) { VMCNT(2); BARRIER(); }
        cur ^= 1;
    }

    // epilogue: direct stores (R12-verified); 32x32 D layout
#pragma unroll
    for (int nt = 0; nt < 2; ++nt) {
        const int col = gn + wn + nt * 32 + l31;
        const float bv = bias[col];
#pragma unroll
        for (int mt = 0; mt < 4; ++mt) {
            f32x16 v = acc[mt][nt];
#pragma unroll
            for (int reg = 0; reg < 16; ++reg) {
                const int row = gm + wm + mt * 32 + (reg & 3) + 8 * (reg >> 2) + 4 * hi;
                const float o = v[reg] + bv;
                if (OUT_F16)
                    ((_Float16*)Cout)[(size_t)row * N + col] = (_Float16)o;
                else
                    ((float*)Cout)[(size_t)row * N + col] = o;
            }
        }
    }
}

// ---------------------------------------------------------------------------
// f16 MFMA flash attention (unchanged from R5-R12).
// ---------------------------------------------------------------------------
#define LOG2E_8 0.18033688f  // 0.125 * log2(e)

#define LOAD_TILE(J0, TAIL)                                                    \
  {                                                                            \
    const int j0_ = (J0);                                                      \
    int jrowK = j0_ + sj;                                                      \
    if (TAIL && jrowK > NN - 1) jrowK = NN - 1;                                \
    const size_t kbase = (size_t)(b * NN + jrowK) * (3 * DIM) + DIM + h * HDIM;\
    k0v = *(const uint4*)&qkv[kbase + sg * 8];                                 \
    k1v = *(const uint4*)&qkv[kbase + sg * 8 + 32];                            \
    int vr0 = j0_ + 2 * jj, vr1 = j0_ + 2 * jj + 1;                            \
    if (TAIL) { if (vr0 > NN - 1) vr0 = NN - 1; if (vr1 > NN - 1) vr1 = NN - 1; } \
    va.v = *(const uint4*)&qkv[(size_t)(b * NN + vr0) * (3 * DIM) + 2 * DIM + h * HDIM + dsub]; \
    vc.v = *(const uint4*)&qkv[(size_t)(b * NN + vr1) * (3 * DIM) + 2 * DIM + h * HDIM + dsub]; \
  }

#define WRITE_TILE(BUF)                                                        \
  {                                                                            \
    _Float16 (*K_)[72] = Ks[BUF];                                              \
    _Float16 (*V_)[72] = Vt[BUF];                                              \
    *(uint4*)&K_[sj][sg * 8]      = k0v;                                       \
    *(uint4*)&K_[sj][sg * 8 + 32] = k1v;                                       \
    _Pragma("unroll")                                                          \
    for (int i = 0; i < 8; ++i) {                                              \
        union { _Float16 h2[2]; unsigned int u; } t;                           \
        t.h2[0] = va.h[i]; t.h2[1] = vc.h[i];                                  \
        *(unsigned int*)&V_[dsub + i][pcol] = t.u;                             \
    }                                                                          \
  }

#define EXP_PACK(SV, G, J0_, TAIL)                                             \
  {                                                                            \
    float p0 = EXP2(SV[0]), p1 = EXP2(SV[1]);                                  \
    float p2 = EXP2(SV[2]), p3 = EXP2(SV[3]);                                  \
    if (TAIL && (J0_ + nt * 16) >= NN) { p0 = p1 = p2 = p3 = 0.f; }            \
    pk[G][nt][0] = pk2(p0, p1, &lpart[G]);                                     \
    pk[G][nt][1] = pk2(p2, p3, &lpart[G]);                                     \
  }

#define COMPUTE_TILE(BUF, J0, TAIL)                                            \
  {                                                                            \
    _Float16 (*K_)[72] = Ks[BUF];                                              \
    _Float16 (*V_)[72] = Vt[BUF];                                              \
    unsigned int pk[2][4][2];                                                  \
    _Pragma("unroll")                                                          \
    for (int nt = 0; nt < 4; ++nt) {                                           \
        f16x8 kf0 = *(const f16x8*)&K_[nt * 16 + l16][quad * 8];               \
        f16x8 kf1 = *(const f16x8*)&K_[nt * 16 + l16][32 + quad * 8];          \
        f32x4 s0 = {}, s1 = {};                                                \
        s0 = __builtin_amdgcn_mfma_f32_16x16x32_f16(kf0, qfrag[0][0], s0, 0, 0, 0); \
        s0 = __builtin_amdgcn_mfma_f32_16x16x32_f16(kf1, qfrag[0][1], s0, 0, 0, 0); \
        s1 = __builtin_amdgcn_mfma_f32_16x16x32_f16(kf0, qfrag[1][0], s1, 0, 0, 0); \
        s1 = __builtin_amdgcn_mfma_f32_16x16x32_f16(kf1, qfrag[1][1], s1, 0, 0, 0); \
        EXP_PACK(s0, 0, J0, TAIL)                                              \
        EXP_PACK(s1, 1, J0, TAIL)                                              \
    }                                                                          \
    __builtin_amdgcn_s_setprio(1);                                             \
    _Pragma("unroll")                                                          \
    for (int pc = 0; pc < 2; ++pc) {                                           \
        union { unsigned int u[4]; f16x8 v; } pa0, pa1;                        \
        pa0.u[0] = pk[0][2 * pc][0];     pa0.u[1] = pk[0][2 * pc][1];          \
        pa0.u[2] = pk[0][2 * pc + 1][0]; pa0.u[3] = pk[0][2 * pc + 1][1];      \
        pa1.u[0] = pk[1][2 * pc][0];     pa1.u[1] = pk[1][2 * pc][1];          \
        pa1.u[2] = pk[1][2 * pc + 1][0]; pa1.u[3] = pk[1][2 * pc + 1][1];      \
        _Pragma("unroll")                                                      \
        for (int dt = 0; dt < 4; ++dt) {                                       \
            f16x8 vf = *(const f16x8*)&V_[dt * 16 + l16][pc * 32 + quad * 8];  \
            O[0][dt] = __builtin_amdgcn_mfma_f32_16x16x32_f16(pa0.v, vf, O[0][dt], 0, 0, 0); \
            O[1][dt] = __builtin_amdgcn_mfma_f32_16x16x32_f16(pa1.v, vf, O[1][dt], 0, 0, 0); \
        }                                                                      \
    }                                                                          \
    __builtin_amdgcn_s_setprio(0);                                             \
  }

__global__ __launch_bounds__(256, 2) void attn_f16_kernel(
    const _Float16* __restrict__ qkv, _Float16* __restrict__ oat)
{
    const int L   = blockIdx.x + 7 * (blockIdx.y + NHEADS * blockIdx.z);
    const int xcd = L & 7, ixc = L >> 3;
    const int grp = xcd * 24 + ixc / 7;
    const int q0  = (ixc % 7) * 128;
    const int b   = grp / NHEADS;
    const int h   = grp % NHEADS;

    const int tid = threadIdx.x;
    const int wave = tid >> 6;
    const int lane = tid & 63;
    const int quad = lane >> 4;
    const int l16  = lane & 15;

    __shared__ _Float16 Ks[2][64][72];
    __shared__ _Float16 Vt[2][64][72];

    f16x8 qfrag[2][2];
#pragma unroll
    for (int g = 0; g < 2; ++g) {
        int qrow = q0 + wave * 32 + g * 16 + l16; if (qrow > NN - 1) qrow = NN - 1;
        size_t base = (size_t)(b * NN + qrow) * (3 * DIM) + h * HDIM;
        qfrag[g][0] = (*(const f16x8*)&qkv[base + quad * 8]) * (_Float16)LOG2E_8;
        qfrag[g][1] = (*(const f16x8*)&qkv[base + 32 + quad * 8]) * (_Float16)LOG2E_8;
    }

    const int sj = lane;
    const int sg = wave;
    const int jj   = lane & 31;
    const int dsub = sg * 16 + (lane >> 5) * 8;
    const int pcol = ((jj >> 4) << 5) | (((jj >> 1) & 3) << 3)
                   | (((jj >> 3) & 1) << 2) | ((jj & 1) << 1);

    f32x4 O[2][4] = {};
    float lpart[2] = {0.f, 0.f};

    uint4 k0v, k1v;
    union { uint4 v; _Float16 h[8]; } va, vc;

    LOAD_TILE(0, 0)
#pragma unroll 1
    for (int jt = 0; jt < 11; ++jt) {
        WRITE_TILE(jt & 1)
        __syncthreads();
        LOAD_TILE((jt + 1) * 64, 0)
        COMPUTE_TILE(jt & 1, 0, 0)
    }
    WRITE_TILE(1)
    __syncthreads();
    LOAD_TILE(768, 1)
    COMPUTE_TILE(1, 704, 0)
    WRITE_TILE(0)
    __syncthreads();
    COMPUTE_TILE(0, 768, 1)

#pragma unroll
    for (int g = 0; g < 2; ++g) {
        float t = lpart[g];
        t += __shfl_xor(t, 16);
        t += __shfl_xor(t, 32);
        float inv[4];
#pragma unroll
        for (int r = 0; r < 4; ++r)
            inv[r] = 1.0f / __shfl(t, quad * 4 + r, 16);
#pragma unroll
        for (int r = 0; r < 4; ++r) {
            const int q = q0 + wave * 32 + g * 16 + quad * 4 + r;
            if (q < NN) {
#pragma unroll
                for (int dt = 0; dt < 4; ++dt) {
                    const size_t base = (size_t)(b * NN + q) * DIM + h * HDIM + dt * 16 + l16;
                    oat[base] = (_Float16)(O[g][dt][r] * inv[r]);
                }
            }
        }
    }
}

// ---------------------------------------------------------------------------
extern "C" void kernel_launch(void* const* d_in, const int* in_sizes, int n_in,
                              void* d_out, int out_size, void* d_ws, size_t ws_size,
                              hipStream_t stream) {
    const float* x    = (const float*)d_in[0];
    const float* Wqkv = (const float*)d_in[1];
    const float* bqkv = (const float*)d_in[2];
    const float* Wo   = (const float*)d_in[3];
    const float* bo   = (const float*)d_in[4];
    float* out = (float*)d_out;

    _Float16* qkv = (_Float16*)d_ws;                    // M x 2304
    _Float16* xh  = qkv + (size_t)M_TOTAL * 3 * DIM;    // M x 768
    _Float16* wqT = xh + (size_t)M_TOTAL * DIM;         // 2304 x 768
    _Float16* woT = wqT + (size_t)3 * DIM * DIM;        // 768 x 768
    _Float16* oat = xh;  // attn out reuses xh (x dead after GEMM1)

    {
        const int NC = (M_TOTAL * DIM) / (8 * 256);               // 4704
        const int NQ = ((3 * DIM) / 32) * (DIM / 32);             // 1728
        const int NO_ = (DIM / 32) * (DIM / 32);                  // 576
        prep_kernel<<<NC + NQ + NO_, 256, 0, stream>>>(
            x, xh, Wqkv, wqT, Wo, woT);
    }
    gemm_f16_kernel<1><<<dim3((3 * DIM) / 256, M_TOTAL / 256), 512, 0, stream>>>(
        xh, wqT, bqkv, qkv, M_TOTAL, 3 * DIM, DIM);
    attn_f16_kernel<<<dim3(7, NHEADS, BB), 256, 0, stream>>>(qkv, oat);
    gemm_f16_kernel<0><<<dim3(DIM / 256, M_TOTAL / 256), 512, 0, stream>>>(
        oat, woT, bo, out, M_TOTAL, DIM, DIM);
}